// Round 5
// baseline (321.907 us; speedup 1.0000x reference)
//
#include <hip/hip_runtime.h>
#include <stdint.h>

// Problem constants
#define B_     16
#define N_     512
#define R_     10
#define DE_    256
#define DR_    64
#define DOUT_  256
#define INDIM_ 3200   // (DE+DR)*R
#define BLK_   320    // DE+DR
#define RN_    5120   // R*N, K-extent of stage B
#define SPLITS_ 5     // stage B split-K factor

typedef __bf16          v8bf  __attribute__((ext_vector_type(8)));
typedef unsigned short  v8us  __attribute__((ext_vector_type(8)));
typedef float           f32x4 __attribute__((ext_vector_type(4)));

static __device__ __forceinline__ unsigned short f2b(float f) {
  union { float f; unsigned u; } c; c.f = f;
  unsigned r = c.u + 0x7FFFu + ((c.u >> 16) & 1u);   // RNE
  return (unsigned short)(r >> 16);
}

static __device__ __forceinline__ v8bf us2bf(v8us u) {
  union { v8us u; v8bf b; } c; c.u = u; return c.b;
}

// async global->LDS, 16B per lane; LDS dest = wave-uniform base + lane*16
static __device__ __forceinline__ void gl_lds16(const void* g, void* l) {
  __builtin_amdgcn_global_load_lds(
      (const __attribute__((address_space(1))) void*)g,
      (__attribute__((address_space(3))) void*)l, 16, 0, 0);
}

// ---------------- prep: node fp32 -> nodeB bf16 [b][m][d] ----------------------
__global__ void prep_nodeB(const float* __restrict__ nf, unsigned short* __restrict__ nodeB) {
  const size_t base = (size_t)blockIdx.x * 8192;
  const int tid = threadIdx.x;
#pragma unroll
  for (int p = 0; p < 4; ++p) {
    size_t off = base + (size_t)p * 2048 + (size_t)tid * 8;
    float4 x = *(const float4*)(nf + off);
    float4 y = *(const float4*)(nf + off + 4);
    v8us u;
    u[0] = f2b(x.x); u[1] = f2b(x.y); u[2] = f2b(x.z); u[3] = f2b(x.w);
    u[4] = f2b(y.x); u[5] = f2b(y.y); u[6] = f2b(y.z); u[7] = f2b(y.w);
    *(v8us*)(nodeB + off) = u;
  }
}

// ---------------- prep: W -> WnB [r][o][d] bf16 (node-part slice) --------------
__global__ void prep_W(const float* __restrict__ W, unsigned short* __restrict__ Wn) {
  int idx = blockIdx.x * 256 + threadIdx.x;        // < R*DOUT*DE = 655360
  int r = idx >> 16;
  int o = (idx >> 8) & 255;
  int d = idx & 255;
  Wn[idx] = f2b(W[(size_t)o * INDIM_ + r * BLK_ + d]);
}

// ---------------- prep: Uf[b][r][o] = sum_dr rel[b,r,dr]*W[o, r*320+256+dr] ----
__global__ void prep_U(const float* __restrict__ rel, const float* __restrict__ W,
                       float* __restrict__ Uf) {
  int idx = blockIdx.x * 256 + threadIdx.x;        // < B*R*DOUT = 40960
  int o  = idx & 255;
  int br = idx >> 8;                                // b*R + r
  int r  = br % R_;
  const float* rp = rel + (size_t)br * DR_;
  const float* wp = W + (size_t)o * INDIM_ + r * BLK_ + DE_;
  float v = 0.f;
#pragma unroll 8
  for (int d = 0; d < DR_; ++d) v += rp[d] * wp[d];
  Uf[idx] = v;
}

// ---------------- stage A: G'[b][o][(r,m)] = Wn[r] @ nodeB[b]^T + U ------------
// Per (b,r): M=256 (o), N=512 (m), K=256 (d). 128x128 tile, BK=64, 4 waves 2x2.
// Both operands bf16 via global_load_lds. Output bf16, k-major for stage B.
__global__ void stageA_gemm(const unsigned short* __restrict__ nodeB,
                            const unsigned short* __restrict__ WnB,
                            const float* __restrict__ Uf,
                            unsigned short* __restrict__ Gp) {
  __shared__ unsigned short Al[128 * 64];   // Wn rows (o)
  __shared__ unsigned short Bl[128 * 64];   // node rows (m)
  const int br = blockIdx.x;                // b*R + r
  const int b  = br / R_, r = br % R_;
  const int o0 = blockIdx.y * 128;
  const int m0 = blockIdx.z * 128;
  const int tid  = threadIdx.x;
  const int lane = tid & 63;
  const int wave = tid >> 6;
  const int wm = wave >> 1, wn = wave & 1;
  const int quad = lane >> 4, l16 = lane & 15;

  const unsigned short* Wb = WnB + (size_t)r * (DOUT_ * DE_);
  const unsigned short* Nb = nodeB + (size_t)b * (N_ * DE_);

  f32x4 acc[4][4];
#pragma unroll
  for (int i = 0; i < 4; ++i)
#pragma unroll
    for (int j = 0; j < 4; ++j) acc[i][j] = f32x4{0.f, 0.f, 0.f, 0.f};

  for (int dk = 0; dk < DE_; dk += 64) {
#pragma unroll
    for (int it = 0; it < 4; ++it) {
      int rowblk = it * 32 + wave * 8;
      int rl = rowblk + (lane >> 3);
      int kc = (lane & 7) ^ (rl & 7);
      gl_lds16(Wb + (size_t)(o0 + rl) * DE_ + dk + kc * 8, Al + rowblk * 64);
      gl_lds16(Nb + (size_t)(m0 + rl) * DE_ + dk + kc * 8, Bl + rowblk * 64);
    }
    __syncthreads();
#pragma unroll
    for (int ks = 0; ks < 2; ++ks) {
      const int kb = ks * 4;
      v8bf av[4], bv[4];
#pragma unroll
      for (int mi = 0; mi < 4; ++mi) {
        int m = wm * 64 + mi * 16 + l16;
        av[mi] = us2bf(*(const v8us*)(Al + m * 64 + (((kb + quad) ^ (m & 7)) * 8)));
      }
#pragma unroll
      for (int ni = 0; ni < 4; ++ni) {
        int c = wn * 64 + ni * 16 + l16;
        bv[ni] = us2bf(*(const v8us*)(Bl + c * 64 + (((kb + quad) ^ (c & 7)) * 8)));
      }
#pragma unroll
      for (int mi = 0; mi < 4; ++mi)
#pragma unroll
        for (int ni = 0; ni < 4; ++ni)
          acc[mi][ni] = __builtin_amdgcn_mfma_f32_16x16x32_bf16(av[mi], bv[ni], acc[mi][ni], 0, 0, 0);
    }
    __syncthreads();
  }

  // epilogue: G'[b][o][r*N + m] = bf16(acc + U[b,r,o])
#pragma unroll
  for (int mi = 0; mi < 4; ++mi)
#pragma unroll
    for (int t = 0; t < 4; ++t) {
      int o = o0 + wm * 64 + mi * 16 + quad * 4 + t;
      float u = Uf[(size_t)br * DOUT_ + o];
      unsigned short* grow = Gp + ((size_t)(b * DOUT_ + o)) * RN_ + r * N_ + m0;
#pragma unroll
      for (int ni = 0; ni < 4; ++ni) {
        int m = wn * 64 + ni * 16 + l16;
        grow[m] = f2b(acc[mi][ni][t] + u);
      }
    }
}

// ---------------- stage B: part[sp][b] = adj[b,2sp:2sp+2](fp32) @ G' slice -----
// Tile 64(n) x 256(o full), split-K=5 (2 relations / block, 16 iters of BK=64).
// Grid 16x8x5 = 640 blocks, 256 thr (4 waves, each 64n x 64o).
// A: fp32 adj -> registers (prefetched one iter ahead) -> bf16 ds_write.
// B: G' bf16 via global_load_lds. Plain stores to per-split partials (no atomics).
__global__ __launch_bounds__(256, 3)
void stageB_gemm(const float* __restrict__ adj,
                 const unsigned short* __restrict__ Gp,
                 float* __restrict__ part) {
  __shared__ unsigned short Al[64 * 64];    // 8 KB
  __shared__ unsigned short Bl[256 * 64];   // 32 KB
  const int b  = blockIdx.x;
  const int n0 = blockIdx.y * 64;
  const int sp = blockIdx.z;                // 0..4 -> relations {2sp, 2sp+1}
  const int tid  = threadIdx.x;
  const int lane = tid & 63;
  const int wave = tid >> 6;
  const int quad = lane >> 4, l16 = lane & 15;

  const float* Ab = adj + (size_t)b * (R_ * N_ * N_);
  const unsigned short* Gb = Gp + (size_t)b * (DOUT_ * RN_);

  f32x4 acc[4][4];
#pragma unroll
  for (int i = 0; i < 4; ++i)
#pragma unroll
    for (int j = 0; j < 4; ++j) acc[i][j] = f32x4{0.f, 0.f, 0.f, 0.f};

  // A staging geometry: thread t covers row (t>>2), 16 floats at colblk (t&3)
  const int arow = tid >> 2;
  const int acb  = tid & 3;
  const float* arp = Ab + (size_t)(n0 + arow) * N_ + acb * 16;  // + r*N*N + mo

  // prologue: prefetch A(it=0): relation 2sp, m-offset 0
  float4 p0, p1, p2, p3;
  {
    const float* g = arp + (size_t)(sp * 2) * (N_ * N_);
    p0 = *(const float4*)(g);
    p1 = *(const float4*)(g + 4);
    p2 = *(const float4*)(g + 8);
    p3 = *(const float4*)(g + 12);
  }

  for (int it = 0; it < 16; ++it) {
    const int r  = sp * 2 + (it >> 3);
    const int k0 = r * N_ + (it & 7) * 64;          // G' k-index of this chunk
    // B tile: G' rows 0..255, k-chunk 64 (async, swizzled slots)
#pragma unroll
    for (int s = 0; s < 8; ++s) {
      int rowblk = s * 32 + wave * 8;
      int rl = rowblk + (lane >> 3);
      int kc = (lane & 7) ^ (rl & 7);
      gl_lds16(Gb + (size_t)rl * RN_ + k0 + kc * 8, Bl + rowblk * 64);
    }
    // A tile: convert prefetched regs -> bf16 -> LDS (swizzled chunks)
    {
      v8us u0, u1;
      u0[0] = f2b(p0.x); u0[1] = f2b(p0.y); u0[2] = f2b(p0.z); u0[3] = f2b(p0.w);
      u0[4] = f2b(p1.x); u0[5] = f2b(p1.y); u0[6] = f2b(p1.z); u0[7] = f2b(p1.w);
      u1[0] = f2b(p2.x); u1[1] = f2b(p2.y); u1[2] = f2b(p2.z); u1[3] = f2b(p2.w);
      u1[4] = f2b(p3.x); u1[5] = f2b(p3.y); u1[6] = f2b(p3.z); u1[7] = f2b(p3.w);
      int c0 = (acb * 2)     ^ (arow & 7);
      int c1 = (acb * 2 + 1) ^ (arow & 7);
      *(v8us*)(Al + arow * 64 + c0 * 8) = u0;
      *(v8us*)(Al + arow * 64 + c1 * 8) = u1;
    }
    // prefetch A(it+1) before the barrier so its latency overlaps B + MFMA
    if (it < 15) {
      const int rn = sp * 2 + ((it + 1) >> 3);
      const float* g = arp + (size_t)rn * (N_ * N_) + ((it + 1) & 7) * 64;
      p0 = *(const float4*)(g);
      p1 = *(const float4*)(g + 4);
      p2 = *(const float4*)(g + 8);
      p3 = *(const float4*)(g + 12);
    }
    __syncthreads();
#pragma unroll
    for (int ks = 0; ks < 2; ++ks) {
      const int kb = ks * 4;
      v8bf av[4], bv[4];
#pragma unroll
      for (int mi = 0; mi < 4; ++mi) {
        int m = mi * 16 + l16;
        av[mi] = us2bf(*(const v8us*)(Al + m * 64 + (((kb + quad) ^ (m & 7)) * 8)));
      }
#pragma unroll
      for (int ni = 0; ni < 4; ++ni) {
        int o = wave * 64 + ni * 16 + l16;
        bv[ni] = us2bf(*(const v8us*)(Bl + o * 64 + (((kb + quad) ^ (o & 7)) * 8)));
      }
#pragma unroll
      for (int mi = 0; mi < 4; ++mi)
#pragma unroll
        for (int ni = 0; ni < 4; ++ni)
          acc[mi][ni] = __builtin_amdgcn_mfma_f32_16x16x32_bf16(av[mi], bv[ni], acc[mi][ni], 0, 0, 0);
    }
    __syncthreads();
  }

  // epilogue: plain coalesced stores to this split's private partial buffer
  float* pb = part + (((size_t)sp * B_ + b) * N_) * DOUT_;
#pragma unroll
  for (int mi = 0; mi < 4; ++mi)
#pragma unroll
    for (int t = 0; t < 4; ++t) {
      int row = n0 + mi * 16 + quad * 4 + t;
#pragma unroll
      for (int ni = 0; ni < 4; ++ni) {
        int col = wave * 64 + ni * 16 + l16;
        pb[(size_t)row * DOUT_ + col] = acc[mi][ni][t];
      }
    }
}

// ---------------- reduce: out = bias + sum_sp part[sp] -------------------------
__global__ void reduce_out(const float* __restrict__ part, const float* __restrict__ bias,
                           float* __restrict__ out) {
  const size_t idx = (size_t)blockIdx.x * 256 + threadIdx.x;  // float4 index
  const size_t stride = (size_t)B_ * N_ * DOUT_ / 4;          // 524288
  f32x4 a = *(const f32x4*)(bias + (idx & 63) * 4);
#pragma unroll
  for (int s = 0; s < SPLITS_; ++s) {
    f32x4 p = *(const f32x4*)((const float*)part + (stride * s + idx) * 4);
    a += p;
  }
  *(f32x4*)(out + idx * 4) = a;
}

// ---------------- launch -------------------------------------------------------
extern "C" void kernel_launch(void* const* d_in, const int* in_sizes, int n_in,
                              void* d_out, int out_size, void* d_ws, size_t ws_size,
                              hipStream_t stream) {
  const float* node = (const float*)d_in[0];
  const float* rel  = (const float*)d_in[1];
  const float* adj  = (const float*)d_in[2];
  const float* W    = (const float*)d_in[3];
  const float* bias = (const float*)d_in[4];
  float* out = (float*)d_out;

  char* ws = (char*)d_ws;
  // layout (~88 MB total):
  unsigned short* nodeB = (unsigned short*)(ws);                      // 4 MB
  unsigned short* WnB   = (unsigned short*)(ws + ((size_t)5 << 20));  // 1.25 MB
  float*          Uf    = (float*)         (ws + ((size_t)7 << 20));  // 160 KB
  unsigned short* Gp    = (unsigned short*)(ws + ((size_t)8 << 20));  // 40 MB
  float*          part  = (float*)         (ws + ((size_t)48 << 20)); // 40 MB (5 x 8MB)

  prep_nodeB<<<dim3((B_ * N_ * DE_) / 8192), 256, 0, stream>>>(node, nodeB);
  prep_W<<<dim3((R_ * DOUT_ * DE_) / 256), 256, 0, stream>>>(W, WnB);
  prep_U<<<dim3((B_ * R_ * DOUT_) / 256), 256, 0, stream>>>(rel, W, Uf);
  stageA_gemm<<<dim3(B_ * R_, DOUT_ / 128, N_ / 128), 256, 0, stream>>>(nodeB, WnB, Uf, Gp);
  stageB_gemm<<<dim3(B_, N_ / 64, SPLITS_), 256, 0, stream>>>(adj, Gp, part);
  reduce_out<<<dim3((B_ * N_ * DOUT_ / 4) / 256), 256, 0, stream>>>(part, bias, out);
}

// Round 6
// 314.904 us; speedup vs baseline: 1.0222x; 1.0222x over previous
//
#include <hip/hip_runtime.h>
#include <stdint.h>

// Problem constants
#define B_     16
#define N_     512
#define R_     10
#define DE_    256
#define DR_    64
#define DOUT_  256
#define INDIM_ 3200   // (DE+DR)*R
#define BLK_   320    // DE+DR
#define RN_    5120   // R*N, K-extent of stage B
#define SPLITS_ 5     // stage B split-K factor

typedef __bf16          v8bf  __attribute__((ext_vector_type(8)));
typedef unsigned short  v8us  __attribute__((ext_vector_type(8)));
typedef unsigned short  v4us  __attribute__((ext_vector_type(4)));
typedef float           f32x4 __attribute__((ext_vector_type(4)));

static __device__ __forceinline__ unsigned short f2b(float f) {
  union { float f; unsigned u; } c; c.f = f;
  unsigned r = c.u + 0x7FFFu + ((c.u >> 16) & 1u);   // RNE
  return (unsigned short)(r >> 16);
}

static __device__ __forceinline__ v8bf us2bf(v8us u) {
  union { v8us u; v8bf b; } c; c.u = u; return c.b;
}

// async global->LDS, 16B per lane; LDS dest = wave-uniform base + lane*16
static __device__ __forceinline__ void gl_lds16(const void* g, void* l) {
  __builtin_amdgcn_global_load_lds(
      (const __attribute__((address_space(1))) void*)g,
      (__attribute__((address_space(3))) void*)l, 16, 0, 0);
}

// ---------------- merged prep: nodeB + WnB + Uf in one launch ------------------
// blocks [0,256): node fp32->bf16 (8192 elems each)
// blocks [256,896): W node-slice -> WnB [r][o][d] bf16 (1024 elems each)
// blocks [896,1056): Uf[b][r][o] = dot(rel[b,r,:], W[o, r*320+256:+64]) (256 ea)
__global__ void prep_all(const float* __restrict__ nf, const float* __restrict__ W,
                         const float* __restrict__ rel,
                         unsigned short* __restrict__ nodeB,
                         unsigned short* __restrict__ WnB,
                         float* __restrict__ Uf) {
  const int bb = blockIdx.x;
  const int tid = threadIdx.x;
  if (bb < 256) {
    const size_t base = (size_t)bb * 8192;
#pragma unroll
    for (int p = 0; p < 4; ++p) {
      size_t off = base + (size_t)p * 2048 + (size_t)tid * 8;
      float4 x = *(const float4*)(nf + off);
      float4 y = *(const float4*)(nf + off + 4);
      v8us u;
      u[0] = f2b(x.x); u[1] = f2b(x.y); u[2] = f2b(x.z); u[3] = f2b(x.w);
      u[4] = f2b(y.x); u[5] = f2b(y.y); u[6] = f2b(y.z); u[7] = f2b(y.w);
      *(v8us*)(nodeB + off) = u;
    }
  } else if (bb < 896) {
    int idx = (bb - 256) * 1024 + tid * 4;          // < 655360, 4-aligned
    int r = idx >> 16;
    int o = (idx >> 8) & 255;
    int d = idx & 255;                               // 4-aligned, stays in row
    float4 x = *(const float4*)(W + (size_t)o * INDIM_ + r * BLK_ + d);
    v4us u;
    u[0] = f2b(x.x); u[1] = f2b(x.y); u[2] = f2b(x.z); u[3] = f2b(x.w);
    *(v4us*)(WnB + idx) = u;
  } else {
    int idx = (bb - 896) * 256 + tid;                // < B*R*DOUT = 40960
    int o  = idx & 255;
    int br = idx >> 8;                                // b*R + r
    int r  = br % R_;
    const float* rp = rel + (size_t)br * DR_;
    const float* wp = W + (size_t)o * INDIM_ + r * BLK_ + DE_;
    float v = 0.f;
#pragma unroll 8
    for (int d = 0; d < DR_; ++d) v += rp[d] * wp[d];
    Uf[idx] = v;
  }
}

// ---------------- stage A: G'[b][o][(r,m)] = Wn[r] @ nodeB[b]^T + U ------------
// Per (b,r): M=256 (o), N=512 (m), K=256 (d). 128x128 tile, BK=64, 4 waves 2x2.
// Both operands bf16 via global_load_lds. Epilogue: LDS transpose (aliasing the
// 32 KB staging buffers) -> coalesced dwordx4 stores of bf16 G'.
__global__ void stageA_gemm(const unsigned short* __restrict__ nodeB,
                            const unsigned short* __restrict__ WnB,
                            const float* __restrict__ Uf,
                            unsigned short* __restrict__ Gp) {
  __shared__ unsigned short S[128 * 128];   // 32 KB: staging (Al|Bl) then C-tile
  unsigned short* Al = S;                   // 128x64 Wn rows (o)
  unsigned short* Bl = S + 128 * 64;        // 128x64 node rows (m)
  const int br = blockIdx.x;                // b*R + r
  const int b  = br / R_, r = br % R_;
  const int o0 = blockIdx.y * 128;
  const int m0 = blockIdx.z * 128;
  const int tid  = threadIdx.x;
  const int lane = tid & 63;
  const int wave = tid >> 6;
  const int wm = wave >> 1, wn = wave & 1;
  const int quad = lane >> 4, l16 = lane & 15;

  const unsigned short* Wb = WnB + (size_t)r * (DOUT_ * DE_);
  const unsigned short* Nb = nodeB + (size_t)b * (N_ * DE_);

  f32x4 acc[4][4];
#pragma unroll
  for (int i = 0; i < 4; ++i)
#pragma unroll
    for (int j = 0; j < 4; ++j) acc[i][j] = f32x4{0.f, 0.f, 0.f, 0.f};

  for (int dk = 0; dk < DE_; dk += 64) {
#pragma unroll
    for (int it = 0; it < 4; ++it) {
      int rowblk = it * 32 + wave * 8;
      int rl = rowblk + (lane >> 3);
      int kc = (lane & 7) ^ (rl & 7);
      gl_lds16(Wb + (size_t)(o0 + rl) * DE_ + dk + kc * 8, Al + rowblk * 64);
      gl_lds16(Nb + (size_t)(m0 + rl) * DE_ + dk + kc * 8, Bl + rowblk * 64);
    }
    __syncthreads();
#pragma unroll
    for (int ks = 0; ks < 2; ++ks) {
      const int kb = ks * 4;
      v8bf av[4], bv[4];
#pragma unroll
      for (int mi = 0; mi < 4; ++mi) {
        int m = wm * 64 + mi * 16 + l16;
        av[mi] = us2bf(*(const v8us*)(Al + m * 64 + (((kb + quad) ^ (m & 7)) * 8)));
      }
#pragma unroll
      for (int ni = 0; ni < 4; ++ni) {
        int c = wn * 64 + ni * 16 + l16;
        bv[ni] = us2bf(*(const v8us*)(Bl + c * 64 + (((kb + quad) ^ (c & 7)) * 8)));
      }
#pragma unroll
      for (int mi = 0; mi < 4; ++mi)
#pragma unroll
        for (int ni = 0; ni < 4; ++ni)
          acc[mi][ni] = __builtin_amdgcn_mfma_f32_16x16x32_bf16(av[mi], bv[ni], acc[mi][ni], 0, 0, 0);
    }
    __syncthreads();
  }

  // epilogue: C tile -> LDS (bf16, +U), then coalesced 16B stores to G'
#pragma unroll
  for (int mi = 0; mi < 4; ++mi)
#pragma unroll
    for (int t = 0; t < 4; ++t) {
      int o_loc = wm * 64 + mi * 16 + quad * 4 + t;
      float u = Uf[(size_t)br * DOUT_ + o0 + o_loc];
#pragma unroll
      for (int ni = 0; ni < 4; ++ni) {
        int m_loc = wn * 64 + ni * 16 + l16;
        S[o_loc * 128 + m_loc] = f2b(acc[mi][ni][t] + u);
      }
    }
  __syncthreads();
#pragma unroll
  for (int p = 0; p < 8; ++p) {
    int idx16 = p * 2048 + tid * 8;         // u16 index into S
    int orow = idx16 >> 7;                  // 0..127
    int moff = idx16 & 127;
    unsigned short* dst = Gp + ((size_t)(b * DOUT_ + o0 + orow)) * RN_ + r * N_ + m0 + moff;
    *(v8us*)dst = *(const v8us*)(S + idx16);
  }
}

// ---------------- stage B: part[sp][b] = adj[b,2sp:2sp+2](fp32) @ G' slice -----
// Tile 32(n) x 256(o full), split-K=5 (2 relations / block, 16 iters of BK=64).
// Grid 16x16x5 = 1280 blocks (~4 resident/CU), 256 thr (4 waves, each 32n x 64o).
// A: fp32 adj -> registers (prefetched one iter ahead) -> bf16 ds_write.
// B: G' bf16 via global_load_lds. Plain stores to per-split partials.
__global__ __launch_bounds__(256, 4)
void stageB_gemm(const float* __restrict__ adj,
                 const unsigned short* __restrict__ Gp,
                 float* __restrict__ part) {
  __shared__ unsigned short Al[32 * 64];    // 4 KB
  __shared__ unsigned short Bl[256 * 64];   // 32 KB
  const int b  = blockIdx.x;
  const int n0 = blockIdx.y * 32;
  const int sp = blockIdx.z;                // 0..4 -> relations {2sp, 2sp+1}
  const int tid  = threadIdx.x;
  const int lane = tid & 63;
  const int wave = tid >> 6;
  const int quad = lane >> 4, l16 = lane & 15;

  const float* Ab = adj + (size_t)b * (R_ * N_ * N_);
  const unsigned short* Gb = Gp + (size_t)b * (DOUT_ * RN_);

  f32x4 acc[2][4];
#pragma unroll
  for (int i = 0; i < 2; ++i)
#pragma unroll
    for (int j = 0; j < 4; ++j) acc[i][j] = f32x4{0.f, 0.f, 0.f, 0.f};

  // A staging geometry: 8 threads/row, each covers 8 floats (32 B)
  const int arow = tid >> 3;                // 0..31
  const int ac8  = tid & 7;                 // which 8-float chunk
  const float* arp = Ab + (size_t)(n0 + arow) * N_ + ac8 * 8;  // + r*N*N + mo

  // prologue: prefetch A(it=0): relation 2sp, m-offset 0
  float4 p0, p1;
  {
    const float* g = arp + (size_t)(sp * 2) * (N_ * N_);
    p0 = *(const float4*)(g);
    p1 = *(const float4*)(g + 4);
  }

  for (int it = 0; it < 16; ++it) {
    const int r  = sp * 2 + (it >> 3);
    const int k0 = r * N_ + (it & 7) * 64;          // G' k-index of this chunk
    // B tile: G' rows 0..255, k-chunk 64 (async, swizzled slots)
#pragma unroll
    for (int s = 0; s < 8; ++s) {
      int rowblk = s * 32 + wave * 8;
      int rl = rowblk + (lane >> 3);
      int kc = (lane & 7) ^ (rl & 7);
      gl_lds16(Gb + (size_t)rl * RN_ + k0 + kc * 8, Bl + rowblk * 64);
    }
    // A tile: convert prefetched regs -> bf16 -> LDS (swizzled chunk)
    {
      v8us u;
      u[0] = f2b(p0.x); u[1] = f2b(p0.y); u[2] = f2b(p0.z); u[3] = f2b(p0.w);
      u[4] = f2b(p1.x); u[5] = f2b(p1.y); u[6] = f2b(p1.z); u[7] = f2b(p1.w);
      int cs = ac8 ^ (arow & 7);
      *(v8us*)(Al + arow * 64 + cs * 8) = u;
    }
    // prefetch A(it+1); stays in flight with the B gl_lds across the barrier
    if (it < 15) {
      const int rn = sp * 2 + ((it + 1) >> 3);
      const float* g = arp + (size_t)rn * (N_ * N_) + ((it + 1) & 7) * 64;
      p0 = *(const float4*)(g);
      p1 = *(const float4*)(g + 4);
    }
    __syncthreads();
#pragma unroll
    for (int ks = 0; ks < 2; ++ks) {
      const int kb = ks * 4;
      v8bf av[2], bv[4];
#pragma unroll
      for (int mi = 0; mi < 2; ++mi) {
        int m = mi * 16 + l16;
        av[mi] = us2bf(*(const v8us*)(Al + m * 64 + (((kb + quad) ^ (m & 7)) * 8)));
      }
#pragma unroll
      for (int ni = 0; ni < 4; ++ni) {
        int o = wave * 64 + ni * 16 + l16;
        bv[ni] = us2bf(*(const v8us*)(Bl + o * 64 + (((kb + quad) ^ (o & 7)) * 8)));
      }
#pragma unroll
      for (int mi = 0; mi < 2; ++mi)
#pragma unroll
        for (int ni = 0; ni < 4; ++ni)
          acc[mi][ni] = __builtin_amdgcn_mfma_f32_16x16x32_bf16(av[mi], bv[ni], acc[mi][ni], 0, 0, 0);
    }
    __syncthreads();
  }

  // epilogue: plain coalesced stores to this split's private partial buffer
  float* pb = part + (((size_t)sp * B_ + b) * N_) * DOUT_;
#pragma unroll
  for (int mi = 0; mi < 2; ++mi)
#pragma unroll
    for (int t = 0; t < 4; ++t) {
      int row = n0 + mi * 16 + quad * 4 + t;
#pragma unroll
      for (int ni = 0; ni < 4; ++ni) {
        int col = wave * 64 + ni * 16 + l16;
        pb[(size_t)row * DOUT_ + col] = acc[mi][ni][t];
      }
    }
}

// ---------------- reduce: out = bias + sum_sp part[sp] -------------------------
__global__ void reduce_out(const float* __restrict__ part, const float* __restrict__ bias,
                           float* __restrict__ out) {
  const size_t idx = (size_t)blockIdx.x * 256 + threadIdx.x;  // float4 index
  const size_t stride = (size_t)B_ * N_ * DOUT_ / 4;          // 524288
  f32x4 a = *(const f32x4*)(bias + (idx & 63) * 4);
#pragma unroll
  for (int s = 0; s < SPLITS_; ++s) {
    f32x4 p = *(const f32x4*)((const float*)part + (stride * s + idx) * 4);
    a += p;
  }
  *(f32x4*)(out + idx * 4) = a;
}

// ---------------- launch -------------------------------------------------------
extern "C" void kernel_launch(void* const* d_in, const int* in_sizes, int n_in,
                              void* d_out, int out_size, void* d_ws, size_t ws_size,
                              hipStream_t stream) {
  const float* node = (const float*)d_in[0];
  const float* rel  = (const float*)d_in[1];
  const float* adj  = (const float*)d_in[2];
  const float* W    = (const float*)d_in[3];
  const float* bias = (const float*)d_in[4];
  float* out = (float*)d_out;

  char* ws = (char*)d_ws;
  // layout (~88 MB total):
  unsigned short* nodeB = (unsigned short*)(ws);                      // 4 MB
  unsigned short* WnB   = (unsigned short*)(ws + ((size_t)5 << 20));  // 1.25 MB
  float*          Uf    = (float*)         (ws + ((size_t)7 << 20));  // 160 KB
  unsigned short* Gp    = (unsigned short*)(ws + ((size_t)8 << 20));  // 40 MB
  float*          part  = (float*)         (ws + ((size_t)48 << 20)); // 40 MB (5 x 8MB)

  prep_all<<<dim3(1056), 256, 0, stream>>>(node, W, rel, nodeB, WnB, Uf);
  stageA_gemm<<<dim3(B_ * R_, DOUT_ / 128, N_ / 128), 256, 0, stream>>>(nodeB, WnB, Uf, Gp);
  stageB_gemm<<<dim3(B_, N_ / 32, SPLITS_), 256, 0, stream>>>(adj, Gp, part);
  reduce_out<<<dim3((B_ * N_ * DOUT_ / 4) / 256), 256, 0, stream>>>(part, bias, out);
}